// Round 10
// baseline (118.434 us; speedup 1.0000x reference)
//
#include <hip/hip_runtime.h>
#include <math.h>

// n=1024, raw=128, d=128, h=256
// prep (257 blocks): blocks 0..255: z = x@W_enc + b_enc (LDS);
//   a' = (z@W1[:d])*log2e; b' = (z@W1[d:]+b1)*log2e; e=exp2(a'), f=exp2(b')
//   f16 half2 planes [k2][n] (k-paired via shfl_xor(1)):
//     PAa=half2{a',a'}, PAe=half2{e,e}, PBb, PBe.
//   block 256: base = b2 - SELU_AS*sum(W2);
//     W2m[k2]=half2{S_OVER_L2E*w}, W2e[k2]=half2{SELU_AS*w}
// pair (grid 16x16, 1024 thr): tile 64x64; quarter q (256 thr) covers
//   k2 in [32q, 32q+32) via two 16-k2 LDS sub-chunks (64 KB static total).
//   Hot loop (per pair, per k2): t2=pk_add; m2=pk_max(t2,0);
//   accm_h=pk_fma(m2,w2m,accm_h); p2=pk_mul; n2=pk_min(p2,1);
//   acce_h=pk_fma(n2,w2e,acce_h)  -- all full-rate VOP3P f16, NO fdot2.
//   Fold to f32 once per 8 k2: acc += fdot2(accm_h,{1,1}) + fdot2(acce_h,{1,1}).
//   (exp2(min(t,0)) == min(Ea*Eb,1) -> no transcendentals in hot loop)
//   Intra-block reduction over quarters in LDS; quarter 0 writes hsig(out).

#define LOG2E       1.4426950408889634f
#define SELU_AS     1.7580993408473766f   // scale*alpha
#define S_OVER_L2E  0.7282921587620419f   // scale/log2e

typedef float v2f __attribute__((ext_vector_type(2)));
typedef _Float16 v2h __attribute__((ext_vector_type(2)));
typedef unsigned int u32;

__global__ __launch_bounds__(256) void prep_kernel(
    const float* __restrict__ x, const float* __restrict__ W_enc,
    const float* __restrict__ b_enc, const float* __restrict__ W1,
    const float* __restrict__ b1, const float* __restrict__ W2,
    const float* __restrict__ b2, u32* __restrict__ PAa,
    u32* __restrict__ PAe, u32* __restrict__ PBb, u32* __restrict__ PBe,
    u32* __restrict__ W2m, u32* __restrict__ W2e, float* __restrict__ basep)
{
    __shared__ float zs[512];
    int t = threadIdx.x, b = blockIdx.x;
    if (b < 256) {
        int r0 = b << 2;
        int r = t >> 6;                   // wave-uniform row 0..3
        int dd = (t & 63) << 1;
        const float* xr = x + (size_t)(r0 + r) * 128;
        v2f z = { b_enc[dd], b_enc[dd + 1] };
#pragma unroll 8
        for (int dl = 0; dl < 128; ++dl) {
            float xv = xr[dl];
            v2f xx = { xv, xv };
            v2f wv = *(const v2f*)(W_enc + (size_t)dl * 128 + dd);
            z = __builtin_elementwise_fma(xx, wv, z);
        }
        zs[r * 128 + dd] = z.x;
        zs[r * 128 + dd + 1] = z.y;
        __syncthreads();

        int c = t;                        // h-column (= k) 0..255
        float b1c = b1[c];
        float accA0 = 0.f, accA1 = 0.f, accA2 = 0.f, accA3 = 0.f;
        float accB0 = b1c, accB1 = b1c, accB2 = b1c, accB3 = b1c;
        const float* w1a = W1 + c;
        const float* w1b = W1 + 128 * 256 + c;
#pragma unroll 4
        for (int dl = 0; dl < 128; ++dl) {
            float wa = w1a[(size_t)dl * 256];
            float wb = w1b[(size_t)dl * 256];
            float z0 = zs[dl], z1 = zs[128 + dl], z2 = zs[256 + dl], z3 = zs[384 + dl];
            accA0 = fmaf(z0, wa, accA0); accB0 = fmaf(z0, wb, accB0);
            accA1 = fmaf(z1, wa, accA1); accB1 = fmaf(z1, wb, accB1);
            accA2 = fmaf(z2, wa, accA2); accB2 = fmaf(z2, wb, accB2);
            accA3 = fmaf(z3, wa, accA3); accB3 = fmaf(z3, wb, accB3);
        }
        float ar[4] = { accA0 * LOG2E, accA1 * LOG2E, accA2 * LOG2E, accA3 * LOG2E };
        float br[4] = { accB0 * LOG2E, accB1 * LOG2E, accB2 * LOG2E, accB3 * LOG2E };
        u32 pa[4], pe[4], pb[4], pf[4];
        bool odd = (c & 1);
#pragma unroll
        for (int r2 = 0; r2 < 4; ++r2) {
            float er = __builtin_amdgcn_exp2f(ar[r2]);
            float fr = __builtin_amdgcn_exp2f(br[r2]);
            float aN = __shfl_xor(ar[r2], 1);
            float eN = __shfl_xor(er, 1);
            float bN = __shfl_xor(br[r2], 1);
            float fN = __shfl_xor(fr, 1);
            pa[r2] = __builtin_bit_cast(u32, __builtin_amdgcn_cvt_pkrtz(ar[r2], aN));
            pe[r2] = __builtin_bit_cast(u32, __builtin_amdgcn_cvt_pkrtz(er, eN));
            pb[r2] = __builtin_bit_cast(u32, __builtin_amdgcn_cvt_pkrtz(bN, br[r2]));
            pf[r2] = __builtin_bit_cast(u32, __builtin_amdgcn_cvt_pkrtz(fN, fr));
        }
        size_t o = (size_t)(c >> 1) * 1024 + r0;    // [k2][n]
        if (!odd) {
            *(uint4*)(PAa + o) = make_uint4(pa[0], pa[1], pa[2], pa[3]);
            *(uint4*)(PAe + o) = make_uint4(pe[0], pe[1], pe[2], pe[3]);
        } else {
            *(uint4*)(PBb + o) = make_uint4(pb[0], pb[1], pb[2], pb[3]);
            *(uint4*)(PBe + o) = make_uint4(pf[0], pf[1], pf[2], pf[3]);
        }
    } else {
        if (t < 128) {
            float w0 = W2[2 * t], w1 = W2[2 * t + 1];
            W2m[t] = __builtin_bit_cast(u32,
                __builtin_amdgcn_cvt_pkrtz(S_OVER_L2E * w0, S_OVER_L2E * w1));
            W2e[t] = __builtin_bit_cast(u32,
                __builtin_amdgcn_cvt_pkrtz(SELU_AS * w0, SELU_AS * w1));
        }
        if (t < 64) {
            float s = W2[t] + W2[t + 64] + W2[t + 128] + W2[t + 192];
#pragma unroll
            for (int o = 32; o > 0; o >>= 1) s += __shfl_down(s, o);
            if (t == 0) basep[0] = fmaf(-SELU_AS, s, b2[0]);
        }
    }
}

// grid (16,16), 1024 threads. Quarter q covers k2 in [32q,32q+32) via two
// 16-k2 sub-chunks in its own 16 KB LDS region. Hot loop is pure pk-f16;
// f32 fold via fdot2({1,1}) every 8 k2.
__global__ __launch_bounds__(1024, 4) void pair_kernel(
    const u32* __restrict__ PAa, const u32* __restrict__ PAe,
    const u32* __restrict__ PBb, const u32* __restrict__ PBe,
    const u32* __restrict__ W2m, const u32* __restrict__ W2e,
    const float* __restrict__ basep, float* __restrict__ out)
{
    __shared__ __align__(16) u32 S[16384];   // 64 KB

    int t = threadIdx.x;
    int q = t >> 8;                 // quarter 0..3
    int tq = t & 255;
    int bj64 = blockIdx.x << 6, bi64 = blockIdx.y << 6;
    int tj4 = (tq & 15) << 2, ti4 = (tq >> 4) << 2;

    u32* Q  = S + (q << 12);        // 4096 u32 = 16 KB per quarter
    u32* Aa = Q;                    // [16 k2][64]
    u32* Ae = Q + 1024;
    u32* Bb = Q + 2048;
    u32* Be = Q + 3072;

    float acc[4][4];
#pragma unroll
    for (int i = 0; i < 4; ++i)
#pragma unroll
        for (int j = 0; j < 4; ++j) acc[i][j] = 0.f;

    const v2h hzero = { (_Float16)0.f, (_Float16)0.f };
    const v2h hone  = { (_Float16)1.f, (_Float16)1.f };

    int s_k2l = tq >> 4;            // staging row 0..15
    int s_jq  = (tq & 15) << 2;     // staging col quad

    for (int sc = 0; sc < 2; ++sc) {
        int k2base = (q << 5) + (sc << 4);
        if (sc) __syncthreads();    // protect LDS reuse
        {
            size_t go = (size_t)(k2base + s_k2l) * 1024;
            *(uint4*)&Aa[tq << 2] = *(const uint4*)(PAa + go + bj64 + s_jq);
            *(uint4*)&Ae[tq << 2] = *(const uint4*)(PAe + go + bj64 + s_jq);
            *(uint4*)&Bb[tq << 2] = *(const uint4*)(PBb + go + bi64 + s_jq);
            *(uint4*)&Be[tq << 2] = *(const uint4*)(PBe + go + bi64 + s_jq);
        }
        __syncthreads();

        const u32* Wm = W2m + k2base;
        const u32* We = W2e + k2base;
#pragma unroll
        for (int h = 0; h < 2; ++h) {       // 8 k2 per f16-accum window
            v2h accm[4][4], acce[4][4];
#pragma unroll
            for (int i = 0; i < 4; ++i)
#pragma unroll
                for (int j = 0; j < 4; ++j) { accm[i][j] = hzero; acce[i][j] = hzero; }
#pragma unroll 4
            for (int kk = 0; kk < 8; ++kk) {
                int k2 = (h << 3) + kk;
                v2h w2m = __builtin_bit_cast(v2h, Wm[k2]);       // uniform
                v2h w2e = __builtin_bit_cast(v2h, We[k2]);
                uint4 qa = *(const uint4*)&Aa[(k2 << 6) + tj4];
                uint4 qe = *(const uint4*)&Ae[(k2 << 6) + tj4];
                uint4 qb = *(const uint4*)&Bb[(k2 << 6) + ti4];
                uint4 qf = *(const uint4*)&Be[(k2 << 6) + ti4];
                v2h a[4] = { __builtin_bit_cast(v2h, qa.x), __builtin_bit_cast(v2h, qa.y),
                             __builtin_bit_cast(v2h, qa.z), __builtin_bit_cast(v2h, qa.w) };
                v2h e[4] = { __builtin_bit_cast(v2h, qe.x), __builtin_bit_cast(v2h, qe.y),
                             __builtin_bit_cast(v2h, qe.z), __builtin_bit_cast(v2h, qe.w) };
                v2h bb[4] = { __builtin_bit_cast(v2h, qb.x), __builtin_bit_cast(v2h, qb.y),
                              __builtin_bit_cast(v2h, qb.z), __builtin_bit_cast(v2h, qb.w) };
                v2h ff[4] = { __builtin_bit_cast(v2h, qf.x), __builtin_bit_cast(v2h, qf.y),
                              __builtin_bit_cast(v2h, qf.z), __builtin_bit_cast(v2h, qf.w) };
#pragma unroll
                for (int i = 0; i < 4; ++i) {
#pragma unroll
                    for (int j = 0; j < 4; ++j) {
                        v2h t2 = a[j] + bb[i];                   // v_pk_add_f16
                        v2h p2 = e[j] * ff[i];                   // v_pk_mul_f16
                        v2h m2 = __builtin_elementwise_max(t2, hzero);
                        v2h n2 = __builtin_elementwise_min(p2, hone);
                        accm[i][j] = __builtin_elementwise_fma(m2, w2m, accm[i][j]);
                        acce[i][j] = __builtin_elementwise_fma(n2, w2e, acce[i][j]);
                    }
                }
            }
            // fold f16 window sums into f32 accumulators (rare fdot2)
#pragma unroll
            for (int i = 0; i < 4; ++i)
#pragma unroll
                for (int j = 0; j < 4; ++j) {
                    acc[i][j] = __builtin_amdgcn_fdot2(accm[i][j], hone, acc[i][j], false);
                    acc[i][j] = __builtin_amdgcn_fdot2(acce[i][j], hone, acc[i][j], false);
                }
        }
    }

    // intra-block reduction across quarters
    __syncthreads();
    if (q != 0) {
        float4* dst = (float4*)Q;                 // 256 thr x 4 float4 = 16 KB
#pragma unroll
        for (int i = 0; i < 4; ++i) {
            float4 v;
            v.x = acc[i][0]; v.y = acc[i][1]; v.z = acc[i][2]; v.w = acc[i][3];
            dst[(tq << 2) + i] = v;
        }
    }
    __syncthreads();
    if (q == 0) {
        float base = basep[0];
        const float4* Q1 = (const float4*)(S + 4096);
        const float4* Q2 = (const float4*)(S + 8192);
        const float4* Q3 = (const float4*)(S + 12288);
#pragma unroll
        for (int i = 0; i < 4; ++i) {
            float4 p1 = Q1[(tq << 2) + i];
            float4 p2 = Q2[(tq << 2) + i];
            float4 p3 = Q3[(tq << 2) + i];
            float v0 = acc[i][0] + p1.x + p2.x + p3.x + base;
            float v1 = acc[i][1] + p1.y + p2.y + p3.y + base;
            float v2 = acc[i][2] + p1.z + p2.z + p3.z + base;
            float v3 = acc[i][3] + p1.w + p2.w + p3.w + base;
            float4 o;
            o.x = __saturatef(v0 * (1.0f / 6.0f) + 0.5f);
            o.y = __saturatef(v1 * (1.0f / 6.0f) + 0.5f);
            o.z = __saturatef(v2 * (1.0f / 6.0f) + 0.5f);
            o.w = __saturatef(v3 * (1.0f / 6.0f) + 0.5f);
            *(float4*)(out + (size_t)(bi64 + ti4 + i) * 1024 + bj64 + tj4) = o;
        }
    }
}

extern "C" void kernel_launch(void* const* d_in, const int* in_sizes, int n_in,
                              void* d_out, int out_size, void* d_ws, size_t ws_size,
                              hipStream_t stream) {
    const float* x     = (const float*)d_in[0];
    const float* W_enc = (const float*)d_in[1];
    const float* b_enc = (const float*)d_in[2];
    const float* W1    = (const float*)d_in[3];
    const float* b1    = (const float*)d_in[4];
    const float* W2    = (const float*)d_in[5];
    const float* b2    = (const float*)d_in[6];
    float* out = (float*)d_out;

    u32* ws = (u32*)d_ws;
    const int PLANE = 128 * 1024;          // u32 per f16 plane = 512 KB
    u32* PAa = ws;
    u32* PAe = ws + PLANE;
    u32* PBb = ws + 2 * PLANE;
    u32* PBe = ws + 3 * PLANE;
    u32* W2m = ws + 4 * PLANE;
    u32* W2e = ws + 4 * PLANE + 128;
    float* basep = (float*)(ws + 4 * PLANE + 256);

    prep_kernel<<<257, 256, 0, stream>>>(x, W_enc, b_enc, W1, b1, W2, b2,
                                         PAa, PAe, PBb, PBe, W2m, W2e, basep);
    pair_kernel<<<dim3(16, 16), 1024, 0, stream>>>(PAa, PAe, PBb, PBe,
                                                   W2m, W2e, basep, out);
}

// Round 11
// 111.812 us; speedup vs baseline: 1.0592x; 1.0592x over previous
//
#include <hip/hip_runtime.h>
#include <math.h>

// n=1024, raw=128, d=128, h=256
// prep (257 blocks): blocks 0..255: z = x@W_enc + b_enc (LDS);
//   a' = (z@W1[:d])*log2e; b' = (z@W1[d:]+b1)*log2e; e=exp2(a'), f=exp2(b')
//   f16 half2 planes [k2][n] (k-paired via shfl_xor(1)):
//     PAa=half2{a',a'}, PAe=half2{e,e}, PBb, PBe.
//   block 256: base = b2 - SELU_AS*sum(W2);
//     W2m[k2]=half2{S_OVER_L2E*w}, W2e[k2]=half2{SELU_AS*w}
// pair (grid 16x16, 512 thr): tile 64x64. Wave w (64 lanes) = K-eighth,
//   k2 in [16w,16w+16), staged as 2 sub-chunks of 8 k2 into a WAVE-PRIVATE
//   8 KB LDS region (8 waves x 8 KB = 64 KB) -> no staging barriers, only
//   in-wave s_waitcnt. Per-thread 8j x 8i register tile: per k2 8
//   ds_read_b128 serve 128 elem-k (half of R9's LDS traffic).
//   t2=a'+b'; p2=e*f; acc += fdot2(max(t2,0),w2m) + fdot2(min(p2,1),w2e)
//   (exp2(min(t,0)) == min(Ea*Eb,1) -> no transcendentals)
//   3-round LDS tree-reduction over the 8 K-eighths; wave 0 writes hsig.

#define LOG2E       1.4426950408889634f
#define SELU_AS     1.7580993408473766f   // scale*alpha
#define S_OVER_L2E  0.7282921587620419f   // scale/log2e

typedef float v2f __attribute__((ext_vector_type(2)));
typedef _Float16 v2h __attribute__((ext_vector_type(2)));
typedef unsigned int u32;

__global__ __launch_bounds__(256) void prep_kernel(
    const float* __restrict__ x, const float* __restrict__ W_enc,
    const float* __restrict__ b_enc, const float* __restrict__ W1,
    const float* __restrict__ b1, const float* __restrict__ W2,
    const float* __restrict__ b2, u32* __restrict__ PAa,
    u32* __restrict__ PAe, u32* __restrict__ PBb, u32* __restrict__ PBe,
    u32* __restrict__ W2m, u32* __restrict__ W2e, float* __restrict__ basep)
{
    __shared__ float zs[512];
    int t = threadIdx.x, b = blockIdx.x;
    if (b < 256) {
        int r0 = b << 2;
        int r = t >> 6;                   // wave-uniform row 0..3
        int dd = (t & 63) << 1;
        const float* xr = x + (size_t)(r0 + r) * 128;
        v2f z = { b_enc[dd], b_enc[dd + 1] };
#pragma unroll 8
        for (int dl = 0; dl < 128; ++dl) {
            float xv = xr[dl];
            v2f xx = { xv, xv };
            v2f wv = *(const v2f*)(W_enc + (size_t)dl * 128 + dd);
            z = __builtin_elementwise_fma(xx, wv, z);
        }
        zs[r * 128 + dd] = z.x;
        zs[r * 128 + dd + 1] = z.y;
        __syncthreads();

        int c = t;                        // h-column (= k) 0..255
        float b1c = b1[c];
        float accA0 = 0.f, accA1 = 0.f, accA2 = 0.f, accA3 = 0.f;
        float accB0 = b1c, accB1 = b1c, accB2 = b1c, accB3 = b1c;
        const float* w1a = W1 + c;
        const float* w1b = W1 + 128 * 256 + c;
#pragma unroll 4
        for (int dl = 0; dl < 128; ++dl) {
            float wa = w1a[(size_t)dl * 256];
            float wb = w1b[(size_t)dl * 256];
            float z0 = zs[dl], z1 = zs[128 + dl], z2 = zs[256 + dl], z3 = zs[384 + dl];
            accA0 = fmaf(z0, wa, accA0); accB0 = fmaf(z0, wb, accB0);
            accA1 = fmaf(z1, wa, accA1); accB1 = fmaf(z1, wb, accB1);
            accA2 = fmaf(z2, wa, accA2); accB2 = fmaf(z2, wb, accB2);
            accA3 = fmaf(z3, wa, accA3); accB3 = fmaf(z3, wb, accB3);
        }
        float ar[4] = { accA0 * LOG2E, accA1 * LOG2E, accA2 * LOG2E, accA3 * LOG2E };
        float br[4] = { accB0 * LOG2E, accB1 * LOG2E, accB2 * LOG2E, accB3 * LOG2E };
        u32 pa[4], pe[4], pb[4], pf[4];
        bool odd = (c & 1);
#pragma unroll
        for (int r2 = 0; r2 < 4; ++r2) {
            float er = __builtin_amdgcn_exp2f(ar[r2]);
            float fr = __builtin_amdgcn_exp2f(br[r2]);
            float aN = __shfl_xor(ar[r2], 1);
            float eN = __shfl_xor(er, 1);
            float bN = __shfl_xor(br[r2], 1);
            float fN = __shfl_xor(fr, 1);
            pa[r2] = __builtin_bit_cast(u32, __builtin_amdgcn_cvt_pkrtz(ar[r2], aN));
            pe[r2] = __builtin_bit_cast(u32, __builtin_amdgcn_cvt_pkrtz(er, eN));
            pb[r2] = __builtin_bit_cast(u32, __builtin_amdgcn_cvt_pkrtz(bN, br[r2]));
            pf[r2] = __builtin_bit_cast(u32, __builtin_amdgcn_cvt_pkrtz(fN, fr));
        }
        size_t o = (size_t)(c >> 1) * 1024 + r0;    // [k2][n]
        if (!odd) {
            *(uint4*)(PAa + o) = make_uint4(pa[0], pa[1], pa[2], pa[3]);
            *(uint4*)(PAe + o) = make_uint4(pe[0], pe[1], pe[2], pe[3]);
        } else {
            *(uint4*)(PBb + o) = make_uint4(pb[0], pb[1], pb[2], pb[3]);
            *(uint4*)(PBe + o) = make_uint4(pf[0], pf[1], pf[2], pf[3]);
        }
    } else {
        if (t < 128) {
            float w0 = W2[2 * t], w1 = W2[2 * t + 1];
            W2m[t] = __builtin_bit_cast(u32,
                __builtin_amdgcn_cvt_pkrtz(S_OVER_L2E * w0, S_OVER_L2E * w1));
            W2e[t] = __builtin_bit_cast(u32,
                __builtin_amdgcn_cvt_pkrtz(SELU_AS * w0, SELU_AS * w1));
        }
        if (t < 64) {
            float s = W2[t] + W2[t + 64] + W2[t + 128] + W2[t + 192];
#pragma unroll
            for (int o = 32; o > 0; o >>= 1) s += __shfl_down(s, o);
            if (t == 0) basep[0] = fmaf(-SELU_AS, s, b2[0]);
        }
    }
}

// grid (16,16), 512 threads = 8 waves. Wave w covers k2 in [16w,16w+16)
// via 2 sub-chunks of 8 k2 in its PRIVATE 8 KB LDS region (no barriers
// during compute). Per-thread 8x8 register tile; tree-reduce at the end.
__global__ __launch_bounds__(512, 2) void pair_kernel(
    const u32* __restrict__ PAa, const u32* __restrict__ PAe,
    const u32* __restrict__ PBb, const u32* __restrict__ PBe,
    const u32* __restrict__ W2m, const u32* __restrict__ W2e,
    const float* __restrict__ basep, float* __restrict__ out)
{
    __shared__ __align__(16) u32 S[16384];   // 64 KB

    int t = threadIdx.x;
    int w = t >> 6;                 // wave / K-eighth 0..7
    int lt = t & 63;
    int bj64 = blockIdx.x << 6, bi64 = blockIdx.y << 6;
    int jb = (lt & 7) << 3;         // j base 0..56
    int ib = (lt >> 3) << 3;        // i base 0..56

    u32* Q  = S + (w << 11);        // 2048 u32 = 8 KB, wave-private
    u32* Aa = Q;                    // [8 k2][64]
    u32* Ae = Q + 512;
    u32* Bb = Q + 1024;
    u32* Be = Q + 1536;

    float acc[8][8];
#pragma unroll
    for (int i = 0; i < 8; ++i)
#pragma unroll
        for (int j = 0; j < 8; ++j) acc[i][j] = 0.f;

    const v2h hzero = { (_Float16)0.f, (_Float16)0.f };
    const v2h hone  = { (_Float16)1.f, (_Float16)1.f };

    for (int sc = 0; sc < 2; ++sc) {
        int k2base = (w << 4) + (sc << 3);
        asm volatile("" ::: "memory");       // keep stage writes after prior reads
        // stage 8 k2 rows x 64 cols per plane; 2 uint4 per plane per thread,
        // stride-1 across the wave (conflict-free)
#pragma unroll
        for (int p = 0; p < 2; ++p) {
            int idx = (p << 6) + lt;         // 0..127
            int row = idx >> 4;
            int col = (idx & 15) << 2;
            size_t go = (size_t)(k2base + row) * 1024;
            *(uint4*)&Aa[idx << 2] = *(const uint4*)(PAa + go + bj64 + col);
            *(uint4*)&Ae[idx << 2] = *(const uint4*)(PAe + go + bj64 + col);
            *(uint4*)&Bb[idx << 2] = *(const uint4*)(PBb + go + bi64 + col);
            *(uint4*)&Be[idx << 2] = *(const uint4*)(PBe + go + bi64 + col);
        }
        asm volatile("s_waitcnt lgkmcnt(0)" ::: "memory");  // wave-private: no barrier

        const u32* Wm = W2m + k2base;
        const u32* We = W2e + k2base;
#pragma unroll 4
        for (int k2 = 0; k2 < 8; ++k2) {
            v2h w2m = __builtin_bit_cast(v2h, Wm[k2]);       // uniform -> s_load
            v2h w2e = __builtin_bit_cast(v2h, We[k2]);
            uint4 qa0 = *(const uint4*)&Aa[(k2 << 6) + jb];
            uint4 qa1 = *(const uint4*)&Aa[(k2 << 6) + jb + 4];
            uint4 qe0 = *(const uint4*)&Ae[(k2 << 6) + jb];
            uint4 qe1 = *(const uint4*)&Ae[(k2 << 6) + jb + 4];
            uint4 qb0 = *(const uint4*)&Bb[(k2 << 6) + ib];
            uint4 qb1 = *(const uint4*)&Bb[(k2 << 6) + ib + 4];
            uint4 qf0 = *(const uint4*)&Be[(k2 << 6) + ib];
            uint4 qf1 = *(const uint4*)&Be[(k2 << 6) + ib + 4];
            v2h A[8] = { __builtin_bit_cast(v2h, qa0.x), __builtin_bit_cast(v2h, qa0.y),
                         __builtin_bit_cast(v2h, qa0.z), __builtin_bit_cast(v2h, qa0.w),
                         __builtin_bit_cast(v2h, qa1.x), __builtin_bit_cast(v2h, qa1.y),
                         __builtin_bit_cast(v2h, qa1.z), __builtin_bit_cast(v2h, qa1.w) };
            v2h E[8] = { __builtin_bit_cast(v2h, qe0.x), __builtin_bit_cast(v2h, qe0.y),
                         __builtin_bit_cast(v2h, qe0.z), __builtin_bit_cast(v2h, qe0.w),
                         __builtin_bit_cast(v2h, qe1.x), __builtin_bit_cast(v2h, qe1.y),
                         __builtin_bit_cast(v2h, qe1.z), __builtin_bit_cast(v2h, qe1.w) };
            v2h B[8] = { __builtin_bit_cast(v2h, qb0.x), __builtin_bit_cast(v2h, qb0.y),
                         __builtin_bit_cast(v2h, qb0.z), __builtin_bit_cast(v2h, qb0.w),
                         __builtin_bit_cast(v2h, qb1.x), __builtin_bit_cast(v2h, qb1.y),
                         __builtin_bit_cast(v2h, qb1.z), __builtin_bit_cast(v2h, qb1.w) };
            v2h F[8] = { __builtin_bit_cast(v2h, qf0.x), __builtin_bit_cast(v2h, qf0.y),
                         __builtin_bit_cast(v2h, qf0.z), __builtin_bit_cast(v2h, qf0.w),
                         __builtin_bit_cast(v2h, qf1.x), __builtin_bit_cast(v2h, qf1.y),
                         __builtin_bit_cast(v2h, qf1.z), __builtin_bit_cast(v2h, qf1.w) };
#pragma unroll
            for (int i = 0; i < 8; ++i) {
#pragma unroll
                for (int j = 0; j < 8; ++j) {
                    v2h t2 = A[j] + B[i];                    // v_pk_add_f16
                    v2h p2 = E[j] * F[i];                    // v_pk_mul_f16
                    v2h m2 = __builtin_elementwise_max(t2, hzero);
                    v2h n2 = __builtin_elementwise_min(p2, hone);
                    acc[i][j] = __builtin_amdgcn_fdot2(m2, w2m, acc[i][j], false);
                    acc[i][j] = __builtin_amdgcn_fdot2(n2, w2e, acc[i][j], false);
                }
            }
        }
    }

    // ---- tree reduction over the 8 K-eighths (regions: 16 KB each) ----
    float4* buf = (float4*)S;
    // [slot(16)][lane(64)] layout per region -> stride-1 wave accesses
#define STORE_ACC(REG) {                                                  \
        float4* r_ = buf + ((REG) << 10);                                 \
        _Pragma("unroll")                                                 \
        for (int i = 0; i < 8; ++i) {                                     \
            float4 lo = { acc[i][0], acc[i][1], acc[i][2], acc[i][3] };   \
            float4 hi = { acc[i][4], acc[i][5], acc[i][6], acc[i][7] };   \
            r_[((i << 1) + 0) * 64 + lt] = lo;                            \
            r_[((i << 1) + 1) * 64 + lt] = hi;                            \
        } }
#define ADD_ACC(REG) {                                                    \
        float4* r_ = buf + ((REG) << 10);                                 \
        _Pragma("unroll")                                                 \
        for (int i = 0; i < 8; ++i) {                                     \
            float4 lo = r_[((i << 1) + 0) * 64 + lt];                     \
            float4 hi = r_[((i << 1) + 1) * 64 + lt];                     \
            acc[i][0] += lo.x; acc[i][1] += lo.y;                         \
            acc[i][2] += lo.z; acc[i][3] += lo.w;                         \
            acc[i][4] += hi.x; acc[i][5] += hi.y;                         \
            acc[i][6] += hi.z; acc[i][7] += hi.w;                         \
        } }

    __syncthreads();
    if (w >= 4) STORE_ACC(w - 4);
    __syncthreads();
    if (w < 4) ADD_ACC(w);
    __syncthreads();
    if (w == 2 || w == 3) STORE_ACC(w - 2);
    __syncthreads();
    if (w < 2) ADD_ACC(w);
    __syncthreads();
    if (w == 1) STORE_ACC(0);
    __syncthreads();
    if (w == 0) {
        ADD_ACC(0);
        float base = basep[0];
#pragma unroll
        for (int i = 0; i < 8; ++i) {
            float4 o0, o1;
            o0.x = __saturatef((acc[i][0] + base) * (1.0f / 6.0f) + 0.5f);
            o0.y = __saturatef((acc[i][1] + base) * (1.0f / 6.0f) + 0.5f);
            o0.z = __saturatef((acc[i][2] + base) * (1.0f / 6.0f) + 0.5f);
            o0.w = __saturatef((acc[i][3] + base) * (1.0f / 6.0f) + 0.5f);
            o1.x = __saturatef((acc[i][4] + base) * (1.0f / 6.0f) + 0.5f);
            o1.y = __saturatef((acc[i][5] + base) * (1.0f / 6.0f) + 0.5f);
            o1.z = __saturatef((acc[i][6] + base) * (1.0f / 6.0f) + 0.5f);
            o1.w = __saturatef((acc[i][7] + base) * (1.0f / 6.0f) + 0.5f);
            size_t orow = (size_t)(bi64 + ib + i) * 1024 + bj64 + jb;
            *(float4*)(out + orow) = o0;
            *(float4*)(out + orow + 4) = o1;
        }
    }
#undef STORE_ACC
#undef ADD_ACC
}

extern "C" void kernel_launch(void* const* d_in, const int* in_sizes, int n_in,
                              void* d_out, int out_size, void* d_ws, size_t ws_size,
                              hipStream_t stream) {
    const float* x     = (const float*)d_in[0];
    const float* W_enc = (const float*)d_in[1];
    const float* b_enc = (const float*)d_in[2];
    const float* W1    = (const float*)d_in[3];
    const float* b1    = (const float*)d_in[4];
    const float* W2    = (const float*)d_in[5];
    const float* b2    = (const float*)d_in[6];
    float* out = (float*)d_out;

    u32* ws = (u32*)d_ws;
    const int PLANE = 128 * 1024;          // u32 per f16 plane = 512 KB
    u32* PAa = ws;
    u32* PAe = ws + PLANE;
    u32* PBb = ws + 2 * PLANE;
    u32* PBe = ws + 3 * PLANE;
    u32* W2m = ws + 4 * PLANE;
    u32* W2e = ws + 4 * PLANE + 128;
    float* basep = (float*)(ws + 4 * PLANE + 256);

    prep_kernel<<<257, 256, 0, stream>>>(x, W_enc, b_enc, W1, b1, W2, b2,
                                         PAa, PAe, PBb, PBe, W2m, W2e, basep);
    pair_kernel<<<dim3(16, 16), 512, 0, stream>>>(PAa, PAe, PBb, PBe,
                                                  W2m, W2e, basep, out);
}

// Round 12
// 103.380 us; speedup vs baseline: 1.1456x; 1.0816x over previous
//
#include <hip/hip_runtime.h>
#include <math.h>

// n=1024, raw=128, d=128, h=256
// prep (257 blocks): blocks 0..255: z = x@W_enc + b_enc (LDS);
//   a' = (z@W1[:d])*log2e; b' = (z@W1[d:]+b1)*log2e; e=exp2(a'), f=exp2(b')
//   f16 half2 planes [k2][n] (k-paired via shfl_xor(1)):
//     PAa=half2{a'/64}, PAe=half2{e}, PBb=half2{b'/64}, PBe=half2{f}.
//   (1/64 prescale => |t'|/64 < 1, so max(t',0)/64 == clamp(a/64+b/64):
//    the VOP3P clamp bit replaces pk_max; e*f>=0 so min(e*f,1)==clamp(e*f)
//    replaces pk_min. Hot loop: 4 instr per pair-k2.)
//   block 256: base = b2 - SELU_AS*sum(W2);
//     W2m[k2]=half2{64*S_OVER_L2E*w}, W2e[k2]=half2{SELU_AS*w}
// pair (grid 16x16, 512 thr): tile 64x64. Wave w = K-eighth, k2 in
//   [16w,16w+16), 2 sub-chunks of 8 k2 in a WAVE-PRIVATE 8 KB LDS region
//   (no staging barriers). 8x8 register tile/thread.
//   acc += fdot2(clamp(a+b), w2m) + fdot2(clamp(e*f), w2e)
//   3-round LDS tree-reduction over K-eighths; wave 0 writes hsig.

#define LOG2E       1.4426950408889634f
#define SELU_AS     1.7580993408473766f   // scale*alpha
#define S_OVER_L2E  0.7282921587620419f   // scale/log2e
#define INV64       0.015625f

typedef float v2f __attribute__((ext_vector_type(2)));
typedef _Float16 v2h __attribute__((ext_vector_type(2)));
typedef unsigned int u32;

__global__ __launch_bounds__(256) void prep_kernel(
    const float* __restrict__ x, const float* __restrict__ W_enc,
    const float* __restrict__ b_enc, const float* __restrict__ W1,
    const float* __restrict__ b1, const float* __restrict__ W2,
    const float* __restrict__ b2, u32* __restrict__ PAa,
    u32* __restrict__ PAe, u32* __restrict__ PBb, u32* __restrict__ PBe,
    u32* __restrict__ W2m, u32* __restrict__ W2e, float* __restrict__ basep)
{
    __shared__ float zs[512];
    int t = threadIdx.x, b = blockIdx.x;
    if (b < 256) {
        int r0 = b << 2;
        int r = t >> 6;                   // wave-uniform row 0..3
        int dd = (t & 63) << 1;
        const float* xr = x + (size_t)(r0 + r) * 128;
        v2f z = { b_enc[dd], b_enc[dd + 1] };
#pragma unroll 8
        for (int dl = 0; dl < 128; ++dl) {
            float xv = xr[dl];
            v2f xx = { xv, xv };
            v2f wv = *(const v2f*)(W_enc + (size_t)dl * 128 + dd);
            z = __builtin_elementwise_fma(xx, wv, z);
        }
        zs[r * 128 + dd] = z.x;
        zs[r * 128 + dd + 1] = z.y;
        __syncthreads();

        int c = t;                        // h-column (= k) 0..255
        float b1c = b1[c];
        float accA0 = 0.f, accA1 = 0.f, accA2 = 0.f, accA3 = 0.f;
        float accB0 = b1c, accB1 = b1c, accB2 = b1c, accB3 = b1c;
        const float* w1a = W1 + c;
        const float* w1b = W1 + 128 * 256 + c;
#pragma unroll 4
        for (int dl = 0; dl < 128; ++dl) {
            float wa = w1a[(size_t)dl * 256];
            float wb = w1b[(size_t)dl * 256];
            float z0 = zs[dl], z1 = zs[128 + dl], z2 = zs[256 + dl], z3 = zs[384 + dl];
            accA0 = fmaf(z0, wa, accA0); accB0 = fmaf(z0, wb, accB0);
            accA1 = fmaf(z1, wa, accA1); accB1 = fmaf(z1, wb, accB1);
            accA2 = fmaf(z2, wa, accA2); accB2 = fmaf(z2, wb, accB2);
            accA3 = fmaf(z3, wa, accA3); accB3 = fmaf(z3, wb, accB3);
        }
        float ar[4] = { accA0 * LOG2E, accA1 * LOG2E, accA2 * LOG2E, accA3 * LOG2E };
        float br[4] = { accB0 * LOG2E, accB1 * LOG2E, accB2 * LOG2E, accB3 * LOG2E };
        u32 pa[4], pe[4], pb[4], pf[4];
        bool odd = (c & 1);
#pragma unroll
        for (int r2 = 0; r2 < 4; ++r2) {
            float er = __builtin_amdgcn_exp2f(ar[r2]);
            float fr = __builtin_amdgcn_exp2f(br[r2]);
            float aN = __shfl_xor(ar[r2], 1);
            float eN = __shfl_xor(er, 1);
            float bN = __shfl_xor(br[r2], 1);
            float fN = __shfl_xor(fr, 1);
            pa[r2] = __builtin_bit_cast(u32,
                __builtin_amdgcn_cvt_pkrtz(ar[r2] * INV64, aN * INV64));
            pe[r2] = __builtin_bit_cast(u32, __builtin_amdgcn_cvt_pkrtz(er, eN));
            pb[r2] = __builtin_bit_cast(u32,
                __builtin_amdgcn_cvt_pkrtz(bN * INV64, br[r2] * INV64));
            pf[r2] = __builtin_bit_cast(u32, __builtin_amdgcn_cvt_pkrtz(fN, fr));
        }
        size_t o = (size_t)(c >> 1) * 1024 + r0;    // [k2][n]
        if (!odd) {
            *(uint4*)(PAa + o) = make_uint4(pa[0], pa[1], pa[2], pa[3]);
            *(uint4*)(PAe + o) = make_uint4(pe[0], pe[1], pe[2], pe[3]);
        } else {
            *(uint4*)(PBb + o) = make_uint4(pb[0], pb[1], pb[2], pb[3]);
            *(uint4*)(PBe + o) = make_uint4(pf[0], pf[1], pf[2], pf[3]);
        }
    } else {
        if (t < 128) {
            float w0 = W2[2 * t], w1 = W2[2 * t + 1];
            const float S64 = S_OVER_L2E * 64.0f;
            W2m[t] = __builtin_bit_cast(u32,
                __builtin_amdgcn_cvt_pkrtz(S64 * w0, S64 * w1));
            W2e[t] = __builtin_bit_cast(u32,
                __builtin_amdgcn_cvt_pkrtz(SELU_AS * w0, SELU_AS * w1));
        }
        if (t < 64) {
            float s = W2[t] + W2[t + 64] + W2[t + 128] + W2[t + 192];
#pragma unroll
            for (int o = 32; o > 0; o >>= 1) s += __shfl_down(s, o);
            if (t == 0) basep[0] = fmaf(-SELU_AS, s, b2[0]);
        }
    }
}

__device__ __forceinline__ v2h clamp2(v2h v) {
    const v2h z = { (_Float16)0.f, (_Float16)0.f };
    const v2h o = { (_Float16)1.f, (_Float16)1.f };
    // minnum(maxnum(x,0),1) -> VOP3P clamp bit on the producing instruction
    return __builtin_elementwise_min(__builtin_elementwise_max(v, z), o);
}

// grid (16,16), 512 threads = 8 waves. Wave w covers k2 in [16w,16w+16)
// via 2 sub-chunks of 8 k2 in its PRIVATE 8 KB LDS region (no barriers
// during compute). Per-thread 8x8 register tile; tree-reduce at the end.
__global__ __launch_bounds__(512, 2) void pair_kernel(
    const u32* __restrict__ PAa, const u32* __restrict__ PAe,
    const u32* __restrict__ PBb, const u32* __restrict__ PBe,
    const u32* __restrict__ W2m, const u32* __restrict__ W2e,
    const float* __restrict__ basep, float* __restrict__ out)
{
    __shared__ __align__(16) u32 S[16384];   // 64 KB

    int t = threadIdx.x;
    int w = t >> 6;                 // wave / K-eighth 0..7
    int lt = t & 63;
    int bj64 = blockIdx.x << 6, bi64 = blockIdx.y << 6;
    int jb = (lt & 7) << 3;         // j base 0..56
    int ib = (lt >> 3) << 3;        // i base 0..56

    u32* Q  = S + (w << 11);        // 2048 u32 = 8 KB, wave-private
    u32* Aa = Q;                    // [8 k2][64]
    u32* Ae = Q + 512;
    u32* Bb = Q + 1024;
    u32* Be = Q + 1536;

    float acc[8][8];
#pragma unroll
    for (int i = 0; i < 8; ++i)
#pragma unroll
        for (int j = 0; j < 8; ++j) acc[i][j] = 0.f;

    for (int sc = 0; sc < 2; ++sc) {
        int k2base = (w << 4) + (sc << 3);
        asm volatile("" ::: "memory");       // keep stage writes after prior reads
#pragma unroll
        for (int p = 0; p < 2; ++p) {
            int idx = (p << 6) + lt;         // 0..127
            int row = idx >> 4;
            int col = (idx & 15) << 2;
            size_t go = (size_t)(k2base + row) * 1024;
            *(uint4*)&Aa[idx << 2] = *(const uint4*)(PAa + go + bj64 + col);
            *(uint4*)&Ae[idx << 2] = *(const uint4*)(PAe + go + bj64 + col);
            *(uint4*)&Bb[idx << 2] = *(const uint4*)(PBb + go + bi64 + col);
            *(uint4*)&Be[idx << 2] = *(const uint4*)(PBe + go + bi64 + col);
        }
        asm volatile("s_waitcnt lgkmcnt(0)" ::: "memory");  // wave-private: no barrier

        const u32* Wm = W2m + k2base;
        const u32* We = W2e + k2base;
#pragma unroll 4
        for (int k2 = 0; k2 < 8; ++k2) {
            v2h w2m = __builtin_bit_cast(v2h, Wm[k2]);       // uniform -> s_load
            v2h w2e = __builtin_bit_cast(v2h, We[k2]);
            uint4 qa0 = *(const uint4*)&Aa[(k2 << 6) + jb];
            uint4 qa1 = *(const uint4*)&Aa[(k2 << 6) + jb + 4];
            uint4 qe0 = *(const uint4*)&Ae[(k2 << 6) + jb];
            uint4 qe1 = *(const uint4*)&Ae[(k2 << 6) + jb + 4];
            uint4 qb0 = *(const uint4*)&Bb[(k2 << 6) + ib];
            uint4 qb1 = *(const uint4*)&Bb[(k2 << 6) + ib + 4];
            uint4 qf0 = *(const uint4*)&Be[(k2 << 6) + ib];
            uint4 qf1 = *(const uint4*)&Be[(k2 << 6) + ib + 4];
            v2h A[8] = { __builtin_bit_cast(v2h, qa0.x), __builtin_bit_cast(v2h, qa0.y),
                         __builtin_bit_cast(v2h, qa0.z), __builtin_bit_cast(v2h, qa0.w),
                         __builtin_bit_cast(v2h, qa1.x), __builtin_bit_cast(v2h, qa1.y),
                         __builtin_bit_cast(v2h, qa1.z), __builtin_bit_cast(v2h, qa1.w) };
            v2h E[8] = { __builtin_bit_cast(v2h, qe0.x), __builtin_bit_cast(v2h, qe0.y),
                         __builtin_bit_cast(v2h, qe0.z), __builtin_bit_cast(v2h, qe0.w),
                         __builtin_bit_cast(v2h, qe1.x), __builtin_bit_cast(v2h, qe1.y),
                         __builtin_bit_cast(v2h, qe1.z), __builtin_bit_cast(v2h, qe1.w) };
            v2h B[8] = { __builtin_bit_cast(v2h, qb0.x), __builtin_bit_cast(v2h, qb0.y),
                         __builtin_bit_cast(v2h, qb0.z), __builtin_bit_cast(v2h, qb0.w),
                         __builtin_bit_cast(v2h, qb1.x), __builtin_bit_cast(v2h, qb1.y),
                         __builtin_bit_cast(v2h, qb1.z), __builtin_bit_cast(v2h, qb1.w) };
            v2h F[8] = { __builtin_bit_cast(v2h, qf0.x), __builtin_bit_cast(v2h, qf0.y),
                         __builtin_bit_cast(v2h, qf0.z), __builtin_bit_cast(v2h, qf0.w),
                         __builtin_bit_cast(v2h, qf1.x), __builtin_bit_cast(v2h, qf1.y),
                         __builtin_bit_cast(v2h, qf1.z), __builtin_bit_cast(v2h, qf1.w) };
#pragma unroll
            for (int i = 0; i < 8; ++i) {
#pragma unroll
                for (int j = 0; j < 8; ++j) {
                    v2h t2 = clamp2(A[j] + B[i]);   // pk_add_f16 + clamp bit
                    v2h p2 = clamp2(E[j] * F[i]);   // pk_mul_f16 + clamp bit
                    acc[i][j] = __builtin_amdgcn_fdot2(t2, w2m, acc[i][j], false);
                    acc[i][j] = __builtin_amdgcn_fdot2(p2, w2e, acc[i][j], false);
                }
            }
        }
    }

    // ---- tree reduction over the 8 K-eighths (regions: 16 KB each) ----
    float4* buf = (float4*)S;
#define STORE_ACC(REG) {                                                  \
        float4* r_ = buf + ((REG) << 10);                                 \
        _Pragma("unroll")                                                 \
        for (int i = 0; i < 8; ++i) {                                     \
            float4 lo = { acc[i][0], acc[i][1], acc[i][2], acc[i][3] };   \
            float4 hi = { acc[i][4], acc[i][5], acc[i][6], acc[i][7] };   \
            r_[((i << 1) + 0) * 64 + lt] = lo;                            \
            r_[((i << 1) + 1) * 64 + lt] = hi;                            \
        } }
#define ADD_ACC(REG) {                                                    \
        float4* r_ = buf + ((REG) << 10);                                 \
        _Pragma("unroll")                                                 \
        for (int i = 0; i < 8; ++i) {                                     \
            float4 lo = r_[((i << 1) + 0) * 64 + lt];                     \
            float4 hi = r_[((i << 1) + 1) * 64 + lt];                     \
            acc[i][0] += lo.x; acc[i][1] += lo.y;                         \
            acc[i][2] += lo.z; acc[i][3] += lo.w;                         \
            acc[i][4] += hi.x; acc[i][5] += hi.y;                         \
            acc[i][6] += hi.z; acc[i][7] += hi.w;                         \
        } }

    __syncthreads();
    if (w >= 4) STORE_ACC(w - 4);
    __syncthreads();
    if (w < 4) ADD_ACC(w);
    __syncthreads();
    if (w == 2 || w == 3) STORE_ACC(w - 2);
    __syncthreads();
    if (w < 2) ADD_ACC(w);
    __syncthreads();
    if (w == 1) STORE_ACC(0);
    __syncthreads();
    if (w == 0) {
        ADD_ACC(0);
        float base = basep[0];
#pragma unroll
        for (int i = 0; i < 8; ++i) {
            float4 o0, o1;
            o0.x = __saturatef((acc[i][0] + base) * (1.0f / 6.0f) + 0.5f);
            o0.y = __saturatef((acc[i][1] + base) * (1.0f / 6.0f) + 0.5f);
            o0.z = __saturatef((acc[i][2] + base) * (1.0f / 6.0f) + 0.5f);
            o0.w = __saturatef((acc[i][3] + base) * (1.0f / 6.0f) + 0.5f);
            o1.x = __saturatef((acc[i][4] + base) * (1.0f / 6.0f) + 0.5f);
            o1.y = __saturatef((acc[i][5] + base) * (1.0f / 6.0f) + 0.5f);
            o1.z = __saturatef((acc[i][6] + base) * (1.0f / 6.0f) + 0.5f);
            o1.w = __saturatef((acc[i][7] + base) * (1.0f / 6.0f) + 0.5f);
            size_t orow = (size_t)(bi64 + ib + i) * 1024 + bj64 + jb;
            *(float4*)(out + orow) = o0;
            *(float4*)(out + orow + 4) = o1;
        }
    }
#undef STORE_ACC
#undef ADD_ACC
}

extern "C" void kernel_launch(void* const* d_in, const int* in_sizes, int n_in,
                              void* d_out, int out_size, void* d_ws, size_t ws_size,
                              hipStream_t stream) {
    const float* x     = (const float*)d_in[0];
    const float* W_enc = (const float*)d_in[1];
    const float* b_enc = (const float*)d_in[2];
    const float* W1    = (const float*)d_in[3];
    const float* b1    = (const float*)d_in[4];
    const float* W2    = (const float*)d_in[5];
    const float* b2    = (const float*)d_in[6];
    float* out = (float*)d_out;

    u32* ws = (u32*)d_ws;
    const int PLANE = 128 * 1024;          // u32 per f16 plane = 512 KB
    u32* PAa = ws;
    u32* PAe = ws + PLANE;
    u32* PBb = ws + 2 * PLANE;
    u32* PBe = ws + 3 * PLANE;
    u32* W2m = ws + 4 * PLANE;
    u32* W2e = ws + 4 * PLANE + 128;
    float* basep = (float*)(ws + 4 * PLANE + 256);

    prep_kernel<<<257, 256, 0, stream>>>(x, W_enc, b_enc, W1, b1, W2, b2,
                                         PAa, PAe, PBb, PBe, W2m, W2e, basep);
    pair_kernel<<<dim3(16, 16), 512, 0, stream>>>(PAa, PAe, PBb, PBe,
                                                  W2m, W2e, basep, out);
}